// Round 7
// baseline (183.046 us; speedup 1.0000x reference)
//
#include <hip/hip_runtime.h>
#include <hip/hip_bf16.h>

#define N_NODES 50000
#define N_EDGES 800000
#define D_IN    1024
#define D_OUT   256
#define CAP     64
#define LEAKY   0.01f

typedef __attribute__((ext_vector_type(8))) short bf16x8;
typedef __attribute__((ext_vector_type(4))) float f32x4;
typedef __attribute__((ext_vector_type(4))) int   i32x4;
typedef unsigned short u16;

__device__ __forceinline__ u16 f2bfu(float f) {
  uint32_t x = __float_as_uint(f);
  uint32_t r = (x + 0x7FFFu + ((x >> 16) & 1u)) >> 16;  // RNE
  return (u16)r;
}
__device__ __forceinline__ float bfu2f(u16 u) {
  return __uint_as_float(((uint32_t)u) << 16);
}
// LDS swizzle for 2048-B rows: XOR byte bits 4-6 with row (byte>>11) low bits.
// ds_read_b128 of 16 rows at one col -> 8 distinct 16B slots x2 lanes = free.
__device__ __forceinline__ int swz2(int b) { return b ^ (((b >> 11) & 7) << 4); }

// ---------------------------------------------------------------------------
// Kernel 1: weight fp32 [K=1024][N=256] -> FRAGMENT-ORDERED bf16 image:
//   img[slab s(4)][kstep t(32)][frag i(4)][lane(64) x 16B]
// where n = s*64 + i*16 + (lane&15), k = t*32 + (lane>>4)*8 .. +8.
// GEMM waves then read W as perfectly-coalesced 1-KB dwordx4 bursts from L2
// (no LDS staging for W at all). Also zeroes deg[].
// ---------------------------------------------------------------------------
__global__ __launch_bounds__(256) void wconv_kernel(const float* __restrict__ w,
                                                    char* __restrict__ img,
                                                    int* __restrict__ deg) {
  const int t = blockIdx.x * 256 + threadIdx.x;   // 0..32767
  if (t < N_NODES) deg[t] = 0;
  const int t2z = t + 32768;
  if (t2z < N_NODES) deg[t2z] = 0;

  const int s   = t >> 13;          // n-slab 0..3
  const int r13 = t & 8191;
  const int tt  = r13 >> 8;         // k-step 0..31
  const int rem = r13 & 255;
  const int i   = rem >> 6;         // frag 0..3
  const int ln  = rem & 63;         // lane
  const int n   = s * 64 + i * 16 + (ln & 15);
  const int k0  = tt * 32 + (ln >> 4) * 8;
  bf16x8 v;
#pragma unroll
  for (int j = 0; j < 8; ++j) v[j] = (short)f2bfu(w[(size_t)(k0 + j) * D_OUT + n]);
  *(bf16x8*)(img + (size_t)t * 16) = v;   // consecutive t -> coalesced store
}

// ---------------------------------------------------------------------------
// Kernel 2 (FUSED): build-blocks + x-stationary GEMM blocks.
//   blocks [0, BUILD_BLOCKS): grid-stride edge-list build (atomics only).
//   blocks [BUILD_BLOCKS, +782): support = x @ W.
// GEMM per block: stage 64x1024 x-tile to LDS ONCE (128 KB, swizzled,
// pure-streaming nontemporal loads), one barrier, then a ZERO-BARRIER
// K-loop: W streamed coalesced from L2 into registers (fragment-ordered
// image), x frags from LDS, 8 MFMA per k-step, pipelined 2 deep.
// ---------------------------------------------------------------------------
#define BM 64
#define GEMM_BLOCKS ((N_NODES + BM - 1) / BM)   // 782
#define BUILD_BLOCKS 64

__global__ __launch_bounds__(512) void gemm_build_kernel(
    const float* __restrict__ x, const char* __restrict__ img,
    u16* __restrict__ support,
    const int* __restrict__ ei, const float* __restrict__ ew,
    int* __restrict__ deg, int2* __restrict__ csr) {
  __shared__ char Xlds[BM * 2048];   // 128 KB: [64 rows][1024 k] bf16, swizzled

  if (blockIdx.x < BUILD_BLOCKS) {
    const int t0 = blockIdx.x * 512 + threadIdx.x;
    for (int e = t0; e < N_EDGES; e += BUILD_BLOCKS * 512) {
      const int src = ei[e];
      const int dst = ei[N_EDGES + e];
      const float w = ew[e];
      const int slot = atomicAdd(&deg[dst], 1);
      if (slot < CAP) csr[dst * CAP + slot] = make_int2(src, __float_as_int(w));
    }
    return;
  }

  const int tid  = threadIdx.x;
  const int lane = tid & 63;
  const int wid  = tid >> 6;
  const int wn   = wid & 3;    // n-slab (64 cols)
  const int wm   = wid >> 2;   // m-half (32 rows)
  const int l15  = lane & 15;
  const int l16  = lane >> 4;
  const int m0   = (blockIdx.x - BUILD_BLOCKS) * BM;

  // ---- stage x tile: row = tid>>3, 8 threads cover a 4-KB row ----
  {
    const int row  = tid >> 3;
    const int col8 = (tid & 7) * 8;                 // float offset
    const int xr   = min(m0 + row, N_NODES - 1);
    const float* xp = x + (size_t)xr * D_IN + col8;
#pragma unroll
    for (int c = 0; c < 16; ++c) {
      const f32x4 a = __builtin_nontemporal_load((const f32x4*)(xp + c * 64));
      const f32x4 b = __builtin_nontemporal_load((const f32x4*)(xp + c * 64 + 4));
      bf16x8 v;
      v[0] = (short)f2bfu(a[0]); v[1] = (short)f2bfu(a[1]);
      v[2] = (short)f2bfu(a[2]); v[3] = (short)f2bfu(a[3]);
      v[4] = (short)f2bfu(b[0]); v[5] = (short)f2bfu(b[1]);
      v[6] = (short)f2bfu(b[2]); v[7] = (short)f2bfu(b[3]);
      *(bf16x8*)(Xlds + swz2(row * 2048 + c * 128 + col8 * 2)) = v;
    }
  }
  __syncthreads();

  // ---- barrier-free K loop: 32 steps of K=32 ----
  f32x4 acc[4][2];
#pragma unroll
  for (int i = 0; i < 4; ++i)
#pragma unroll
    for (int j = 0; j < 2; ++j) acc[i][j] = (f32x4)0.0f;

  // W: img + wn*131072 + t*4096 + i*1024 + lane*16  (coalesced 1KB/instr)
  const char* wp = img + (size_t)wn * 131072 + lane * 16;
  // x frags: row = wm*32 + j*16 + l15, byte col = t*64 + l16*16 (swizzled)
  int xoff[2];
#pragma unroll
  for (int j = 0; j < 2; ++j)
    xoff[j] = (wm * 32 + j * 16 + l15) * 2048 + l16 * 16;

  bf16x8 afA[4], afB[4], bbA[2], bbB[2];
#pragma unroll
  for (int i = 0; i < 4; ++i) afA[i] = *(const bf16x8*)(wp + i * 1024);
#pragma unroll
  for (int j = 0; j < 2; ++j) bbA[j] = *(const bf16x8*)(Xlds + swz2(xoff[j]));

  for (int t = 0; t < 32; t += 2) {
    // prefetch t+1 (always valid: t odd max = 31)
#pragma unroll
    for (int i = 0; i < 4; ++i)
      afB[i] = *(const bf16x8*)(wp + (t + 1) * 4096 + i * 1024);
#pragma unroll
    for (int j = 0; j < 2; ++j)
      bbB[j] = *(const bf16x8*)(Xlds + swz2(xoff[j] + (t + 1) * 64));
#pragma unroll
    for (int i = 0; i < 4; ++i)
#pragma unroll
      for (int j = 0; j < 2; ++j)
        acc[i][j] = __builtin_amdgcn_mfma_f32_16x16x32_bf16(afA[i], bbA[j], acc[i][j], 0, 0, 0);
    if (t < 30) {
#pragma unroll
      for (int i = 0; i < 4; ++i)
        afA[i] = *(const bf16x8*)(wp + (t + 2) * 4096 + i * 1024);
#pragma unroll
      for (int j = 0; j < 2; ++j)
        bbA[j] = *(const bf16x8*)(Xlds + swz2(xoff[j] + (t + 2) * 64));
    }
#pragma unroll
    for (int i = 0; i < 4; ++i)
#pragma unroll
      for (int j = 0; j < 2; ++j)
        acc[i][j] = __builtin_amdgcn_mfma_f32_16x16x32_bf16(afB[i], bbB[j], acc[i][j], 0, 0, 0);
  }

  // D: m = m0 + wm*32 + j*16 + l15 (col idx), n = wn*64 + i*16 + l16*4 + reg.
#pragma unroll
  for (int j = 0; j < 2; ++j) {
    const int m = m0 + wm * 32 + j * 16 + l15;
    if (m < N_NODES) {
#pragma unroll
      for (int i = 0; i < 4; ++i) {
        const int n = wn * 64 + i * 16 + l16 * 4;
        ushort4 o;
        o.x = f2bfu(acc[i][j][0]);
        o.y = f2bfu(acc[i][j][1]);
        o.z = f2bfu(acc[i][j][2]);
        o.w = f2bfu(acc[i][j][3]);
        *(ushort4*)&support[(size_t)m * D_OUT + n] = o;
      }
    }
  }
}

// ---------------------------------------------------------------------------
// Kernel 3: per-node gather-aggregate + epilogue. One wave per node,
// 16-deep gather pipeline (unchanged from round 5 -- measured ~20 us).
// ---------------------------------------------------------------------------
__global__ __launch_bounds__(256) void agg_kernel(const u16* __restrict__ support,
                                                  const int* __restrict__ deg,
                                                  const int2* __restrict__ csr,
                                                  const float* __restrict__ norm,
                                                  const float* __restrict__ bias,
                                                  float* __restrict__ out) {
  const int lane = threadIdx.x & 63;
  const int wid  = threadIdx.x >> 6;
  const int node = blockIdx.x * 4 + wid;   // grid 12500 -> exactly 50000
  const int d    = min(deg[node], CAP);
  const int cb   = node * CAP;
  const int ch   = lane * 4;

  float a0 = 0.f, a1 = 0.f, a2 = 0.f, a3 = 0.f;
  int s = 0;

  for (; s + 16 <= d; s += 16) {
    i32x4 q[8];
#pragma unroll
    for (int i = 0; i < 8; ++i)
      q[i] = __builtin_nontemporal_load((const i32x4*)&csr[cb + s + 2 * i]);
    ushort4 v[16];
#pragma unroll
    for (int i = 0; i < 8; ++i) {
      v[2 * i]     = *(const ushort4*)&support[(size_t)q[i][0] * D_OUT + ch];
      v[2 * i + 1] = *(const ushort4*)&support[(size_t)q[i][2] * D_OUT + ch];
    }
#pragma unroll
    for (int i = 0; i < 8; ++i) {
      const float wa = __int_as_float(q[i][1]);
      const float wb = __int_as_float(q[i][3]);
      a0 = fmaf(wa, bfu2f(v[2 * i].x), a0);
      a1 = fmaf(wa, bfu2f(v[2 * i].y), a1);
      a2 = fmaf(wa, bfu2f(v[2 * i].z), a2);
      a3 = fmaf(wa, bfu2f(v[2 * i].w), a3);
      a0 = fmaf(wb, bfu2f(v[2 * i + 1].x), a0);
      a1 = fmaf(wb, bfu2f(v[2 * i + 1].y), a1);
      a2 = fmaf(wb, bfu2f(v[2 * i + 1].z), a2);
      a3 = fmaf(wb, bfu2f(v[2 * i + 1].w), a3);
    }
  }

  for (; s + 8 <= d; s += 8) {
    i32x4 q[4];
#pragma unroll
    for (int i = 0; i < 4; ++i)
      q[i] = __builtin_nontemporal_load((const i32x4*)&csr[cb + s + 2 * i]);
    ushort4 v[8];
#pragma unroll
    for (int i = 0; i < 4; ++i) {
      v[2 * i]     = *(const ushort4*)&support[(size_t)q[i][0] * D_OUT + ch];
      v[2 * i + 1] = *(const ushort4*)&support[(size_t)q[i][2] * D_OUT + ch];
    }
#pragma unroll
    for (int i = 0; i < 4; ++i) {
      const float wa = __int_as_float(q[i][1]);
      const float wb = __int_as_float(q[i][3]);
      a0 = fmaf(wa, bfu2f(v[2 * i].x), a0);
      a1 = fmaf(wa, bfu2f(v[2 * i].y), a1);
      a2 = fmaf(wa, bfu2f(v[2 * i].z), a2);
      a3 = fmaf(wa, bfu2f(v[2 * i].w), a3);
      a0 = fmaf(wb, bfu2f(v[2 * i + 1].x), a0);
      a1 = fmaf(wb, bfu2f(v[2 * i + 1].y), a1);
      a2 = fmaf(wb, bfu2f(v[2 * i + 1].z), a2);
      a3 = fmaf(wb, bfu2f(v[2 * i + 1].w), a3);
    }
  }

  for (; s < d; ++s) {
    const int2  e   = csr[cb + s];
    const float wgt = __int_as_float(e.y);
    const ushort4 v = *(const ushort4*)&support[(size_t)e.x * D_OUT + ch];
    a0 = fmaf(wgt, bfu2f(v.x), a0);
    a1 = fmaf(wgt, bfu2f(v.y), a1);
    a2 = fmaf(wgt, bfu2f(v.z), a2);
    a3 = fmaf(wgt, bfu2f(v.w), a3);
  }

  const float rn = 1.0f / norm[node];
  const float4 b = *(const float4*)&bias[ch];
  float o0 = fmaf(a0, rn, b.x);
  float o1 = fmaf(a1, rn, b.y);
  float o2 = fmaf(a2, rn, b.z);
  float o3 = fmaf(a3, rn, b.w);
  o0 = o0 > 0.f ? o0 : o0 * LEAKY;
  o1 = o1 > 0.f ? o1 : o1 * LEAKY;
  o2 = o2 > 0.f ? o2 : o2 * LEAKY;
  o3 = o3 > 0.f ? o3 : o3 * LEAKY;
  f32x4 ov;
  ov[0] = o0; ov[1] = o1; ov[2] = o2; ov[3] = o3;
  __builtin_nontemporal_store(ov, (f32x4*)&out[(size_t)node * D_OUT + ch]);
}

// ---------------------------------------------------------------------------
// ws layout (bytes):
//   support  bf16  [50000][256]       @ 0          25,600,000
//   Wimg     bf16  frag-ordered       @ 25,600,000    524,288
//   csr      int2  [50000][64]        @ 26,124,288 25,600,000
//   deg      int   [50000]            @ 51,724,288    200,000
// ---------------------------------------------------------------------------
extern "C" void kernel_launch(void* const* d_in, const int* in_sizes, int n_in,
                              void* d_out, int out_size, void* d_ws, size_t ws_size,
                              hipStream_t stream) {
  const float* x    = (const float*)d_in[0];
  const float* w    = (const float*)d_in[1];
  const float* bias = (const float*)d_in[2];
  const int*   ei   = (const int*)d_in[3];
  const float* ew   = (const float*)d_in[4];
  const float* norm = (const float*)d_in[5];
  float* out = (float*)d_out;

  char* ws = (char*)d_ws;
  u16*   support = (u16*)  (ws);
  char*  img     =         (ws + 25600000);
  int2*  csr     = (int2*) (ws + 26124288);
  int*   deg     = (int*)  (ws + 51724288);

  wconv_kernel<<<128, 256, 0, stream>>>(w, img, deg);
  gemm_build_kernel<<<BUILD_BLOCKS + GEMM_BLOCKS, 512, 0, stream>>>(
      x, img, support, ei, ew, deg, csr);
  agg_kernel<<<N_NODES / 4, 256, 0, stream>>>(support, deg, csr, norm, bias, out);
}

// Round 8
// 168.379 us; speedup vs baseline: 1.0871x; 1.0871x over previous
//
#include <hip/hip_runtime.h>
#include <hip/hip_bf16.h>

#define N_NODES 50000
#define N_EDGES 800000
#define D_IN    1024
#define D_OUT   256
#define CAP     64
#define LEAKY   0.01f

typedef __attribute__((ext_vector_type(8))) short bf16x8;
typedef __attribute__((ext_vector_type(4))) float f32x4;
typedef __attribute__((ext_vector_type(4))) int   i32x4;
typedef unsigned short u16;

__device__ __forceinline__ u16 f2bfu(float f) {
  uint32_t x = __float_as_uint(f);
  uint32_t r = (x + 0x7FFFu + ((x >> 16) & 1u)) >> 16;  // RNE
  return (u16)r;
}
__device__ __forceinline__ float bfu2f(u16 u) {
  return __uint_as_float(((uint32_t)u) << 16);
}
// XOR bank swizzle within an 8-KB / 32-KB tile: flip byte bits 4-6 with row.
__device__ __forceinline__ int swz(int b) { return b ^ (((b >> 7) & 7) << 4); }

__device__ __forceinline__ void gll16(const void* g, void* l) {
  __builtin_amdgcn_global_load_lds(
      (const __attribute__((address_space(1))) uint32_t*)g,
      (__attribute__((address_space(3))) uint32_t*)l, 16, 0, 0);
}

// ---------------------------------------------------------------------------
// Kernel 1 (r6 layout, coalesced reads): weight fp32 [1024][256] -> bf16
// swizzled image, 16 k-tiles x [256 n][64 k] x 32768 B. Also zeroes deg[].
// ---------------------------------------------------------------------------
__global__ __launch_bounds__(256) void wconv_kernel(const float* __restrict__ w,
                                                    char* __restrict__ img,
                                                    int* __restrict__ deg) {
  const int t   = blockIdx.x * 256 + threadIdx.x;   // 0..32767
  if (t < N_NODES) deg[t] = 0;
  const int t2 = t + 32768;
  if (t2 < N_NODES) deg[t2] = 0;

  const int n   = t & 255;          // consecutive threads -> consecutive n
  const int kc  = (t >> 8) * 8;
  const int kt  = kc >> 6;
  const int kin = kc & 63;
  bf16x8 v;
#pragma unroll
  for (int i = 0; i < 8; ++i) v[i] = (short)f2bfu(w[(size_t)(kc + i) * D_OUT + n]);
  *(bf16x8*)(img + kt * 32768 + swz(n * 128 + kin * 2)) = v;
}

// ---------------------------------------------------------------------------
// Kernel 2 (FUSED build + GEMM), 3-deep counted-vmcnt pipeline.
// Per K-iteration (tile kt, buffers b = kt%3):
//   issue x(kt+2) loads (2 vm)  -> reg set (kt+2)%3      [oldest-first!]
//   issue gll W(kt+2) (4 vm)    -> Wbuf[(kt+2)%3]
//   ds_read frags of tile kt from Wbuf/Xbuf[b]; 16 MFMA
//   cvt x(kt+1) -> ds_write Xbuf[(kt+1)%3]   (auto-wait = vmcnt(6))
//   asm vmcnt(6); sched_barrier; lgkmcnt(0); s_barrier   [NEVER drains to 0]
// 6 VMEM ops stay in flight across every barrier; each load has a full
// iteration of slack -> queue latency amortized instead of paid 16x.
// ---------------------------------------------------------------------------
#define BM 64
#define BK 64
#define KSTEPS (D_IN / BK)   // 16
#define GEMM_BLOCKS ((N_NODES + BM - 1) / BM)   // 782
#define BUILD_BLOCKS 64

__global__ __launch_bounds__(512) void gemm_build_kernel(
    const float* __restrict__ x, const char* __restrict__ img,
    u16* __restrict__ support,
    const int* __restrict__ ei, const float* __restrict__ ew,
    int* __restrict__ deg, int2* __restrict__ csr) {
  __shared__ u16 Wbuf[3][16384];  // 3 x 32 KB, [256 n][64 k] swizzled
  __shared__ u16 Xbuf[3][4096];   // 3 x  8 KB, [64 m][64 k] swizzled

  if (blockIdx.x < BUILD_BLOCKS) {
    const int t0 = blockIdx.x * 512 + threadIdx.x;
    for (int e = t0; e < N_EDGES; e += BUILD_BLOCKS * 512) {
      const int src = ei[e];
      const int dst = ei[N_EDGES + e];
      const float w = ew[e];
      const int slot = atomicAdd(&deg[dst], 1);
      if (slot < CAP) csr[dst * CAP + slot] = make_int2(src, __float_as_int(w));
    }
    return;
  }

  const int tid  = threadIdx.x;
  const int lane = tid & 63;
  const int wid  = tid >> 6;
  const int wn   = wid & 3;
  const int wm   = wid >> 2;
  const int l15  = lane & 15;
  const int l16  = lane >> 4;
  const int m0   = (blockIdx.x - BUILD_BLOCKS) * BM;

  f32x4 acc[4][2];
#pragma unroll
  for (int i = 0; i < 4; ++i)
#pragma unroll
    for (int j = 0; j < 2; ++j) acc[i][j] = (f32x4)0.0f;

  const int xrow = tid >> 3;           // 0..63
  const int xk8  = (tid & 7) * 8;      // 0..56
  const int xrg  = min(m0 + xrow, N_NODES - 1);
  const float* xp = x + (size_t)xrg * D_IN + xk8;
  const int xw_off = swz(xrow * 128 + xk8 * 2);   // within 8-KB tile

  int a_off[2][4], b_off[2][2];
#pragma unroll
  for (int ks = 0; ks < 2; ++ks) {
#pragma unroll
    for (int i = 0; i < 4; ++i)
      a_off[ks][i] = swz((wn * 64 + i * 16 + l15) * 128 + ks * 64 + l16 * 16);
#pragma unroll
    for (int j = 0; j < 2; ++j)
      b_off[ks][j] = swz((wm * 32 + j * 16 + l15) * 128 + ks * 64 + l16 * 16);
  }

  float4 xr[3][2];   // 3 rotating x reg sets (literal-indexed via macros)

#define XLOAD(set, tile) do {                                              \
    const int kcl_ = min((tile), KSTEPS - 1);                              \
    xr[set][0] = *(const float4*)(xp + kcl_ * BK);                         \
    xr[set][1] = *(const float4*)(xp + kcl_ * BK + 4);                     \
  } while (0)

#define WSTAGE(buf, tile) do {                                             \
    const int kcl_ = min((tile), KSTEPS - 1);                              \
    _Pragma("unroll")                                                      \
    for (int r_ = 0; r_ < 4; ++r_)                                         \
      gll16(img + kcl_ * 32768 + r_ * 8192 + tid * 16,                     \
            (char*)&Wbuf[buf][0] + r_ * 8192 + tid * 16);                  \
  } while (0)

#define XCVT(set, buf) do {                                                \
    bf16x8 xv_;                                                            \
    xv_[0] = (short)f2bfu(xr[set][0].x); xv_[1] = (short)f2bfu(xr[set][0].y); \
    xv_[2] = (short)f2bfu(xr[set][0].z); xv_[3] = (short)f2bfu(xr[set][0].w); \
    xv_[4] = (short)f2bfu(xr[set][1].x); xv_[5] = (short)f2bfu(xr[set][1].y); \
    xv_[6] = (short)f2bfu(xr[set][1].z); xv_[7] = (short)f2bfu(xr[set][1].w); \
    *(bf16x8*)((char*)&Xbuf[buf][0] + xw_off) = xv_;                       \
  } while (0)

#define MFMA_TILE(buf) do {                                                \
    _Pragma("unroll")                                                      \
    for (int ks_ = 0; ks_ < 2; ++ks_) {                                    \
      bf16x8 af_[4], bf_[2];                                               \
      _Pragma("unroll")                                                    \
      for (int i_ = 0; i_ < 4; ++i_)                                       \
        af_[i_] = *(const bf16x8*)((const char*)&Wbuf[buf][0] + a_off[ks_][i_]); \
      _Pragma("unroll")                                                    \
      for (int j_ = 0; j_ < 2; ++j_)                                       \
        bf_[j_] = *(const bf16x8*)((const char*)&Xbuf[buf][0] + b_off[ks_][j_]); \
      _Pragma("unroll")                                                    \
      for (int i_ = 0; i_ < 4; ++i_)                                       \
        _Pragma("unroll")                                                  \
        for (int j_ = 0; j_ < 2; ++j_)                                     \
          acc[i_][j_] = __builtin_amdgcn_mfma_f32_16x16x32_bf16(           \
              af_[i_], bf_[j_], acc[i_][j_], 0, 0, 0);                     \
    }                                                                      \
  } while (0)

#define SYNC_COUNTED() do {                                                \
    asm volatile("s_waitcnt vmcnt(6)" ::: "memory");                       \
    __builtin_amdgcn_sched_barrier(0);                                     \
    asm volatile("s_waitcnt lgkmcnt(0)" ::: "memory");                     \
    __builtin_amdgcn_s_barrier();                                          \
  } while (0)

#define BODY(bc, kt) do {                                                  \
    XLOAD((bc + 2) % 3, (kt) + 2);                                         \
    WSTAGE((bc + 2) % 3, (kt) + 2);                                        \
    MFMA_TILE(bc);                                                         \
    XCVT((bc + 1) % 3, (bc + 1) % 3);                                      \
    SYNC_COUNTED();                                                        \
  } while (0)

  // ---- prologue: tiles 0 and 1 in flight, Xbuf[0] written ----
  XLOAD(0, 0);
  WSTAGE(0, 0);
  XLOAD(1, 1);
  WSTAGE(1, 1);
  XCVT(0, 0);
  SYNC_COUNTED();   // ensures gll(0) done (x(1)+gll(1)=6 remain in flight)

  // ---- main loop: tiles 0..14, unrolled x3 with literal buffer indices ----
  for (int kt = 0; kt < KSTEPS - 1; kt += 3) {
    BODY(0, kt);
    BODY(1, kt + 1);
    BODY(2, kt + 2);
  }
  // ---- tail: tile 15 (buffers 0, already synced) ----
  MFMA_TILE(0);

#undef XLOAD
#undef WSTAGE
#undef XCVT
#undef MFMA_TILE
#undef SYNC_COUNTED
#undef BODY

  // D: m = m0 + wm*32 + j*16 + l15, n = wn*64 + i*16 + l16*4 + reg.
#pragma unroll
  for (int j = 0; j < 2; ++j) {
    const int m = m0 + wm * 32 + j * 16 + l15;
    if (m < N_NODES) {
#pragma unroll
      for (int i = 0; i < 4; ++i) {
        const int n = wn * 64 + i * 16 + l16 * 4;
        ushort4 o;
        o.x = f2bfu(acc[i][j][0]);
        o.y = f2bfu(acc[i][j][1]);
        o.z = f2bfu(acc[i][j][2]);
        o.w = f2bfu(acc[i][j][3]);
        *(ushort4*)&support[(size_t)m * D_OUT + n] = o;
      }
    }
  }
}

// ---------------------------------------------------------------------------
// Kernel 3: per-node gather-aggregate + epilogue (r5/r6 version, ~20 us).
// ---------------------------------------------------------------------------
__global__ __launch_bounds__(256) void agg_kernel(const u16* __restrict__ support,
                                                  const int* __restrict__ deg,
                                                  const int2* __restrict__ csr,
                                                  const float* __restrict__ norm,
                                                  const float* __restrict__ bias,
                                                  float* __restrict__ out) {
  const int lane = threadIdx.x & 63;
  const int wid  = threadIdx.x >> 6;
  const int node = blockIdx.x * 4 + wid;   // grid 12500 -> exactly 50000
  const int d    = min(deg[node], CAP);
  const int cb   = node * CAP;
  const int ch   = lane * 4;

  float a0 = 0.f, a1 = 0.f, a2 = 0.f, a3 = 0.f;
  int s = 0;

  for (; s + 16 <= d; s += 16) {
    i32x4 q[8];
#pragma unroll
    for (int i = 0; i < 8; ++i)
      q[i] = __builtin_nontemporal_load((const i32x4*)&csr[cb + s + 2 * i]);
    ushort4 v[16];
#pragma unroll
    for (int i = 0; i < 8; ++i) {
      v[2 * i]     = *(const ushort4*)&support[(size_t)q[i][0] * D_OUT + ch];
      v[2 * i + 1] = *(const ushort4*)&support[(size_t)q[i][2] * D_OUT + ch];
    }
#pragma unroll
    for (int i = 0; i < 8; ++i) {
      const float wa = __int_as_float(q[i][1]);
      const float wb = __int_as_float(q[i][3]);
      a0 = fmaf(wa, bfu2f(v[2 * i].x), a0);
      a1 = fmaf(wa, bfu2f(v[2 * i].y), a1);
      a2 = fmaf(wa, bfu2f(v[2 * i].z), a2);
      a3 = fmaf(wa, bfu2f(v[2 * i].w), a3);
      a0 = fmaf(wb, bfu2f(v[2 * i + 1].x), a0);
      a1 = fmaf(wb, bfu2f(v[2 * i + 1].y), a1);
      a2 = fmaf(wb, bfu2f(v[2 * i + 1].z), a2);
      a3 = fmaf(wb, bfu2f(v[2 * i + 1].w), a3);
    }
  }

  for (; s + 8 <= d; s += 8) {
    i32x4 q[4];
#pragma unroll
    for (int i = 0; i < 4; ++i)
      q[i] = __builtin_nontemporal_load((const i32x4*)&csr[cb + s + 2 * i]);
    ushort4 v[8];
#pragma unroll
    for (int i = 0; i < 4; ++i) {
      v[2 * i]     = *(const ushort4*)&support[(size_t)q[i][0] * D_OUT + ch];
      v[2 * i + 1] = *(const ushort4*)&support[(size_t)q[i][2] * D_OUT + ch];
    }
#pragma unroll
    for (int i = 0; i < 4; ++i) {
      const float wa = __int_as_float(q[i][1]);
      const float wb = __int_as_float(q[i][3]);
      a0 = fmaf(wa, bfu2f(v[2 * i].x), a0);
      a1 = fmaf(wa, bfu2f(v[2 * i].y), a1);
      a2 = fmaf(wa, bfu2f(v[2 * i].z), a2);
      a3 = fmaf(wa, bfu2f(v[2 * i].w), a3);
      a0 = fmaf(wb, bfu2f(v[2 * i + 1].x), a0);
      a1 = fmaf(wb, bfu2f(v[2 * i + 1].y), a1);
      a2 = fmaf(wb, bfu2f(v[2 * i + 1].z), a2);
      a3 = fmaf(wb, bfu2f(v[2 * i + 1].w), a3);
    }
  }

  for (; s < d; ++s) {
    const int2  e   = csr[cb + s];
    const float wgt = __int_as_float(e.y);
    const ushort4 v = *(const ushort4*)&support[(size_t)e.x * D_OUT + ch];
    a0 = fmaf(wgt, bfu2f(v.x), a0);
    a1 = fmaf(wgt, bfu2f(v.y), a1);
    a2 = fmaf(wgt, bfu2f(v.z), a2);
    a3 = fmaf(wgt, bfu2f(v.w), a3);
  }

  const float rn = 1.0f / norm[node];
  const float4 b = *(const float4*)&bias[ch];
  float o0 = fmaf(a0, rn, b.x);
  float o1 = fmaf(a1, rn, b.y);
  float o2 = fmaf(a2, rn, b.z);
  float o3 = fmaf(a3, rn, b.w);
  o0 = o0 > 0.f ? o0 : o0 * LEAKY;
  o1 = o1 > 0.f ? o1 : o1 * LEAKY;
  o2 = o2 > 0.f ? o2 : o2 * LEAKY;
  o3 = o3 > 0.f ? o3 : o3 * LEAKY;
  f32x4 ov;
  ov[0] = o0; ov[1] = o1; ov[2] = o2; ov[3] = o3;
  __builtin_nontemporal_store(ov, (f32x4*)&out[(size_t)node * D_OUT + ch]);
}

// ---------------------------------------------------------------------------
// ws layout (bytes):
//   support  bf16  [50000][256]     @ 0          25,600,000
//   Wimg     bf16  16x[256][64] swz @ 25,600,000    524,288
//   csr      int2  [50000][64]      @ 26,124,288 25,600,000
//   deg      int   [50000]          @ 51,724,288    200,000
// ---------------------------------------------------------------------------
extern "C" void kernel_launch(void* const* d_in, const int* in_sizes, int n_in,
                              void* d_out, int out_size, void* d_ws, size_t ws_size,
                              hipStream_t stream) {
  const float* x    = (const float*)d_in[0];
  const float* w    = (const float*)d_in[1];
  const float* bias = (const float*)d_in[2];
  const int*   ei   = (const int*)d_in[3];
  const float* ew   = (const float*)d_in[4];
  const float* norm = (const float*)d_in[5];
  float* out = (float*)d_out;

  char* ws = (char*)d_ws;
  u16*   support = (u16*)  (ws);
  char*  img     =         (ws + 25600000);
  int2*  csr     = (int2*) (ws + 26124288);
  int*   deg     = (int*)  (ws + 51724288);

  wconv_kernel<<<128, 256, 0, stream>>>(w, img, deg);
  gemm_build_kernel<<<BUILD_BLOCKS + GEMM_BLOCKS, 512, 0, stream>>>(
      x, img, support, ei, ew, deg, csr);
  agg_kernel<<<N_NODES / 4, 256, 0, stream>>>(support, deg, csr, norm, bias, out);
}